// Round 3
// baseline (59.701 us; speedup 1.0000x reference)
//
#include <hip/hip_runtime.h>
#include <stdint.h>

// BERT input representation, round 3: coalesced-store design.
//   out = x@W + seg + b_emb*(1+Sw) + b_seg + PE   (M=32768, K=64, N=1024)
//
// setup kernel: W f32 -> bf16 MFMA-A-fragment layout in d_ws (128 KB).
// main kernel: 512 blocks x 256 thr, 2 blocks/CU. Block = 128 rows x 512 cols,
//   4 slabs of 32 rows. Swapped-operand MFMA (W as A, x as B) -> lane holds 4
//   consecutive out-cols. Epilogue (seg butterfly + inline PE) writes to a
//   XOR-swizzled 64KB LDS buffer; stores are then 1KB-contiguous dwordx4.

typedef __attribute__((ext_vector_type(8))) short short8;
typedef __attribute__((ext_vector_type(4))) float f32x4;

#define D_DIM 1024

__device__ __forceinline__ unsigned short f2bf(float f) {
  unsigned u = __float_as_uint(f);
  u = (u + 0x7FFFu + ((u >> 16) & 1u)) >> 16;  // RNE f32 -> bf16
  return (unsigned short)u;
}

// ---- W -> bf16 A-fragment layout (layout verified by round 2 pass) ----
// t = (cfg*2 + kf)*64 + lane; elem i = W[kf*32 + (lane>>4)*8 + i][cfg*16 + (lane&15)]
__global__ __launch_bounds__(256) void bert_wconv(const float* __restrict__ W,
                                                  unsigned short* __restrict__ wsW) {
  const int t = blockIdx.x * 256 + threadIdx.x;  // 8192 threads
  const int lane = t & 63;
  const int kf = (t >> 6) & 1;
  const int cfg = t >> 7;
  const int col = cfg * 16 + (lane & 15);
  const int k0 = kf * 32 + ((lane >> 4) << 3);
  short8 o;
#pragma unroll
  for (int i = 0; i < 8; ++i)
    o[i] = (short)f2bf(W[(size_t)(k0 + i) * D_DIM + col]);
  *reinterpret_cast<short8*>(wsW + (size_t)t * 8) = o;
}

__global__ __launch_bounds__(256, 2) void bert_main(
    const float* __restrict__ x, const unsigned short* __restrict__ wsW,
    const float* __restrict__ b_emb, const float* __restrict__ w_seg,
    const float* __restrict__ b_seg, float* __restrict__ out) {
  __shared__ unsigned short ldsx[32 * 64];  // 4 KB x-slab, XOR-swizzled
  __shared__ float ldse[32 * 512];          // 64 KB epilogue, XOR-swizzled
  char* const ldsxB = (char*)ldsx;
  char* const ldseB = (char*)ldse;

  const int tid = threadIdx.x;
  const int lane = tid & 63;
  const int w = tid >> 6;
  const int L15 = lane & 15;
  const int g = lane >> 4;
  const int h = blockIdx.x & 1;    // col half (512 cols)
  const int rg = blockIdx.x >> 1;  // row group (128 rows)
  const int wcol = h * 512 + w * 128;

  // A fragments for this wave's 128 cols, held in registers all kernel.
  short8 aW[8][2];
#pragma unroll
  for (int cf = 0; cf < 8; ++cf)
#pragma unroll
    for (int kf = 0; kf < 2; ++kf)
      aW[cf][kf] = *reinterpret_cast<const short8*>(
          wsW + ((size_t)(((wcol >> 4) + cf) * 2 + kf) * 64 + lane) * 8);

  float Sw = 0.f;
#pragma unroll
  for (int i = 0; i < 8; ++i) Sw += w_seg[i];
  const float s1w = 1.f + Sw;
  const float bseg = b_seg[0];
  const float tseg = w_seg[L15 & 7];  // row-in-segment weight (rows are L15-indexed)

  // PE column constants, hoisted: 2 exp2 per 4-col group.
  const float inv2pi = 0.15915494309189535f;
  const float KLOG = 0.02595256324130752f;  // log2(10000)/512
  float divr[8][2];
#pragma unroll
  for (int cf = 0; cf < 8; ++cf) {
    const int p = (wcol + cf * 16 + g * 4) >> 1;
    divr[cf][0] = exp2f(-(float)p * KLOG) * inv2pi;
    divr[cf][1] = exp2f(-(float)(p + 1) * KLOG) * inv2pi;
  }

  for (int it = 0; it < 4; ++it) {
    const int rbase = rg * 128 + it * 32;

    // ---- stage x slab (32 rows x 64 f32) -> LDS bf16, swizzled ----
    {
      const int r = tid >> 3;
      const int c8 = (tid & 7) * 8;
      const float* xp = x + (size_t)(rbase + r) * 64 + c8;
      const float4 v0 = *reinterpret_cast<const float4*>(xp);
      const float4 v1 = *reinterpret_cast<const float4*>(xp + 4);
      short8 o;
      o[0] = (short)f2bf(v0.x); o[1] = (short)f2bf(v0.y);
      o[2] = (short)f2bf(v0.z); o[3] = (short)f2bf(v0.w);
      o[4] = (short)f2bf(v1.x); o[5] = (short)f2bf(v1.y);
      o[6] = (short)f2bf(v1.z); o[7] = (short)f2bf(v1.w);
      *reinterpret_cast<short8*>(
          ldsxB + ((r * 128 + c8 * 2) ^ ((r & 7) << 4))) = o;
    }
    __syncthreads();

    // ---- B fragments + MFMA ----
    short8 bX[2][2];
#pragma unroll
    for (int rf = 0; rf < 2; ++rf)
#pragma unroll
      for (int kf = 0; kf < 2; ++kf) {
        const int r = rf * 16 + L15;
        bX[rf][kf] = *reinterpret_cast<const short8*>(
            ldsxB + ((r * 128 + kf * 64 + g * 16) ^ ((r & 7) << 4)));
      }

    f32x4 acc[8][2];
#pragma unroll
    for (int cf = 0; cf < 8; ++cf)
#pragma unroll
      for (int rf = 0; rf < 2; ++rf) {
        f32x4 c = {0.f, 0.f, 0.f, 0.f};
        c = __builtin_amdgcn_mfma_f32_16x16x32_bf16(aW[cf][0], bX[rf][0], c, 0, 0, 0);
        c = __builtin_amdgcn_mfma_f32_16x16x32_bf16(aW[cf][1], bX[rf][1], c, 0, 0, 0);
        acc[cf][rf] = c;
      }

    // ---- epilogue: seg reduce + PE + biases -> swizzled LDS ----
#pragma unroll
    for (int cf = 0; cf < 8; ++cf) {
      const int c0 = wcol + cf * 16 + g * 4;
      const float4 eb = *reinterpret_cast<const float4*>(b_emb + c0);
#pragma unroll
      for (int rf = 0; rf < 2; ++rf) {
        f32x4 a = acc[cf][rf];
        float q0 = a[0] * tseg, q1 = a[1] * tseg, q2 = a[2] * tseg, q3 = a[3] * tseg;
        q0 += __shfl_xor(q0, 1); q1 += __shfl_xor(q1, 1);
        q2 += __shfl_xor(q2, 1); q3 += __shfl_xor(q3, 1);
        q0 += __shfl_xor(q0, 2); q1 += __shfl_xor(q1, 2);
        q2 += __shfl_xor(q2, 2); q3 += __shfl_xor(q3, 2);
        q0 += __shfl_xor(q0, 4); q1 += __shfl_xor(q1, 4);
        q2 += __shfl_xor(q2, 4); q3 += __shfl_xor(q3, 4);

        const int r = rf * 16 + L15;
        const float s = (float)((rbase + r) & 511);
        const float pe0 = __builtin_amdgcn_sinf(__builtin_amdgcn_fractf(s * divr[cf][0]));
        const float pe1 = __builtin_amdgcn_sinf(__builtin_amdgcn_fractf(s * divr[cf][0] + 0.25f));
        const float pe2 = __builtin_amdgcn_sinf(__builtin_amdgcn_fractf(s * divr[cf][1]));
        const float pe3 = __builtin_amdgcn_sinf(__builtin_amdgcn_fractf(s * divr[cf][1] + 0.25f));

        f32x4 o;
        o[0] = a[0] + q0 + pe0 + eb.x * s1w + bseg;
        o[1] = a[1] + q1 + pe1 + eb.y * s1w + bseg;
        o[2] = a[2] + q2 + pe2 + eb.z * s1w + bseg;
        o[3] = a[3] + q3 + pe3 + eb.w * s1w + bseg;

        const int colh = w * 128 + cf * 16 + g * 4;  // col within 512-half
        *reinterpret_cast<f32x4*>(
            ldseB + (((r * 512 + colh) * 4) ^ ((r & 7) << 4))) = o;
      }
    }
    __syncthreads();

    // ---- coalesced store: 1KB-contiguous dwordx4 per wave-instruction ----
#pragma unroll
    for (int p = 0; p < 16; ++p) {
      const int flat = p * 1024 + tid * 4;  // f32 index in 32x512 slab
      const int r = flat >> 9;
      const int c = flat & 511;
      const f32x4 v = *reinterpret_cast<const f32x4*>(
          ldseB + ((flat * 4) ^ ((r & 7) << 4)));
      *reinterpret_cast<f32x4*>(out + (size_t)(rbase + r) * D_DIM + h * 512 + c) = v;
    }
    // no barrier needed: next x-stage touches ldsx only; next ldse write is
    // after the next __syncthreads(), by which all store-reads have drained.
  }
}

extern "C" void kernel_launch(void* const* d_in, const int* in_sizes, int n_in,
                              void* d_out, int out_size, void* d_ws,
                              size_t ws_size, hipStream_t stream) {
  const float* x = (const float*)d_in[0];
  const float* W = (const float*)d_in[1];
  const float* b_emb = (const float*)d_in[2];
  const float* w_seg = (const float*)d_in[3];
  const float* b_seg = (const float*)d_in[4];
  float* out = (float*)d_out;
  unsigned short* wsW = (unsigned short*)d_ws;  // 128 KB

  bert_wconv<<<32, 256, 0, stream>>>(W, wsW);
  bert_main<<<512, 256, 0, stream>>>(x, wsW, b_emb, w_seg, b_seg, out);
}

// Round 4
// 39.379 us; speedup vs baseline: 1.5161x; 1.5161x over previous
//
#include <hip/hip_runtime.h>
#include <stdint.h>

// BERT input representation, round 4: round-2 structure (which ran at memory
// roofline for its traffic) minus the fatal 134MB PE table -> PE inline.
//   out = x@W + seg + b_emb*(1+Sw) + b_seg + PE   (M=32768, K=64, N=1024)
//
// setup kernel (one launch):
//   d_ws[0,128KB)        W bf16 in MFMA-A-fragment order
//   d_ws[128KB,128KB+4MB) x bf16 row-major [32768][64]
// main kernel: 4096 blocks x 256 thr, no LDS, no barriers. Swapped-operand
//   MFMA (W as A, x as B) -> each lane's f32x4 = 4 consecutive out-cols.
//   Epilogue: seg butterfly (shfl_xor 1,2,4), inline PE with hoisted exp2,
//   float4 stores (16 rows x 64B per wave-inst — proven roofline in round 2).

typedef __attribute__((ext_vector_type(8))) short short8;
typedef __attribute__((ext_vector_type(4))) float f32x4;

#define D_DIM 1024
#define WS_X_OFF 131072

__device__ __forceinline__ unsigned short f2bf(float f) {
  unsigned u = __float_as_uint(f);
  u = (u + 0x7FFFu + ((u >> 16) & 1u)) >> 16;  // RNE f32 -> bf16
  return (unsigned short)u;
}

__global__ __launch_bounds__(256) void bert_setup(
    const float* __restrict__ x, const float* __restrict__ W,
    unsigned short* __restrict__ wsW, unsigned short* __restrict__ wsX) {
  const int bid = blockIdx.x;
  const int tid = threadIdx.x;
  if (bid < 1024) {
    // ---- x f32 -> bf16, 8 elems/thread ----
    const int t = bid * 256 + tid;
    const float4* p = reinterpret_cast<const float4*>(x) + (size_t)t * 2;
    float4 v0 = p[0], v1 = p[1];
    short8 o;
    o[0] = (short)f2bf(v0.x); o[1] = (short)f2bf(v0.y);
    o[2] = (short)f2bf(v0.z); o[3] = (short)f2bf(v0.w);
    o[4] = (short)f2bf(v1.x); o[5] = (short)f2bf(v1.y);
    o[6] = (short)f2bf(v1.z); o[7] = (short)f2bf(v1.w);
    *reinterpret_cast<short8*>(wsX + (size_t)t * 8) = o;
  } else {
    // ---- W -> bf16 A-fragment layout ----
    // t=(cfg*2+kf)*64+lane; elem i = W[kf*32+(lane>>4)*8+i][cfg*16+(lane&15)]
    const int t = (bid - 1024) * 256 + tid;  // 0..8191
    const int cfg = t >> 7;
    const int kf = (t >> 6) & 1;
    const int lane = t & 63;
    const int col = cfg * 16 + (lane & 15);
    const int k0 = kf * 32 + ((lane >> 4) << 3);
    short8 o;
#pragma unroll
    for (int i = 0; i < 8; ++i)
      o[i] = (short)f2bf(W[(size_t)(k0 + i) * D_DIM + col]);
    *reinterpret_cast<short8*>(wsW + (size_t)t * 8) = o;
  }
}

__global__ __launch_bounds__(256) void bert_main(
    const unsigned short* __restrict__ wsX,
    const unsigned short* __restrict__ wsW, const float* __restrict__ b_emb,
    const float* __restrict__ w_seg, const float* __restrict__ b_seg,
    float* __restrict__ out) {
  const int tid = threadIdx.x;
  const int lane = tid & 63;
  const int wave = tid >> 6;
  const int bid = blockIdx.x;
  // XCD swizzle: bids sharing (bid&7) -> same XCD, which then owns whole
  // 64-row stripes across all 8 col-blocks (x rows hit HBM once per chip).
  const int nblk = (bid >> 3) & 7;
  const int mblk = (bid & 7) | ((bid >> 6) << 3);
  const int mbase = mblk * 64;
  const int nbase = nblk * 128;
  const int mw = wave >> 1;  // row half (32 rows)
  const int nw = wave & 1;   // col half (64 cols)
  const int L15 = lane & 15;
  const int g = lane >> 4;

  // ---- A fragments: W cols (M dim), L2-hot ----
  short8 aW[4][2];
#pragma unroll
  for (int cf = 0; cf < 4; ++cf)
#pragma unroll
    for (int kf = 0; kf < 2; ++kf) {
      const int cfg = (nbase >> 4) + nw * 4 + cf;
      aW[cf][kf] = *reinterpret_cast<const short8*>(
          wsW + ((size_t)(cfg * 2 + kf) * 64 + lane) * 8);
    }

  // ---- B fragments: x rows (N dim) ----
  short8 bX[2][2];
#pragma unroll
  for (int rf = 0; rf < 2; ++rf)
#pragma unroll
    for (int kf = 0; kf < 2; ++kf) {
      const int row = mbase + mw * 32 + rf * 16 + L15;
      bX[rf][kf] = *reinterpret_cast<const short8*>(
          wsX + (size_t)row * 64 + kf * 32 + g * 8);
    }

  // ---- MFMA: D[m=out-col][n=out-row] ----
  f32x4 acc[4][2];
#pragma unroll
  for (int cf = 0; cf < 4; ++cf)
#pragma unroll
    for (int rf = 0; rf < 2; ++rf) {
      f32x4 c = {0.f, 0.f, 0.f, 0.f};
      c = __builtin_amdgcn_mfma_f32_16x16x32_bf16(aW[cf][0], bX[rf][0], c, 0, 0, 0);
      c = __builtin_amdgcn_mfma_f32_16x16x32_bf16(aW[cf][1], bX[rf][1], c, 0, 0, 0);
      acc[cf][rf] = c;
    }

  // ---- epilogue constants ----
  float Sw = 0.f;
#pragma unroll
  for (int i = 0; i < 8; ++i) Sw += w_seg[i];
  const float s1w = 1.f + Sw;
  const float bseg = b_seg[0];
  const float tseg = w_seg[lane & 7];  // row-in-segment weight

  // PE frequencies, hoisted: lane owns cols colq..colq+3 -> 2 freqs per cf.
  const float inv2pi = 0.15915494309189535f;
  const float KLOG = 0.02595256324130752f;  // log2(10000)/512
  float dv[4][2];
#pragma unroll
  for (int cf = 0; cf < 4; ++cf) {
    const int p = (nbase + nw * 64 + cf * 16 + g * 4) >> 1;
    dv[cf][0] = exp2f(-(float)p * KLOG) * inv2pi;
    dv[cf][1] = exp2f(-(float)(p + 1) * KLOG) * inv2pi;
  }

  // ---- fused epilogue: seg butterfly + inline PE + biases + store ----
#pragma unroll
  for (int cf = 0; cf < 4; ++cf) {
    const int colq = nbase + nw * 64 + cf * 16 + g * 4;
    const float4 eb = *reinterpret_cast<const float4*>(b_emb + colq);
    const float e0 = eb.x * s1w + bseg, e1 = eb.y * s1w + bseg;
    const float e2 = eb.z * s1w + bseg, e3 = eb.w * s1w + bseg;
#pragma unroll
    for (int rf = 0; rf < 2; ++rf) {
      f32x4 a = acc[cf][rf];
      // segment reduce over the 8 rows (lane bits 0..2 index row-in-segment)
      float q0 = a[0] * tseg, q1 = a[1] * tseg, q2 = a[2] * tseg, q3 = a[3] * tseg;
      q0 += __shfl_xor(q0, 1); q1 += __shfl_xor(q1, 1);
      q2 += __shfl_xor(q2, 1); q3 += __shfl_xor(q3, 1);
      q0 += __shfl_xor(q0, 2); q1 += __shfl_xor(q1, 2);
      q2 += __shfl_xor(q2, 2); q3 += __shfl_xor(q3, 2);
      q0 += __shfl_xor(q0, 4); q1 += __shfl_xor(q1, 4);
      q2 += __shfl_xor(q2, 4); q3 += __shfl_xor(q3, 4);

      const int row = mbase + mw * 32 + rf * 16 + L15;
      const float s = (float)(row & 511);
      const float pe0 = __builtin_amdgcn_sinf(__builtin_amdgcn_fractf(s * dv[cf][0]));
      const float pe1 = __builtin_amdgcn_sinf(__builtin_amdgcn_fractf(s * dv[cf][0] + 0.25f));
      const float pe2 = __builtin_amdgcn_sinf(__builtin_amdgcn_fractf(s * dv[cf][1]));
      const float pe3 = __builtin_amdgcn_sinf(__builtin_amdgcn_fractf(s * dv[cf][1] + 0.25f));

      float4 o;
      o.x = a[0] + q0 + pe0 + e0;
      o.y = a[1] + q1 + pe1 + e1;
      o.z = a[2] + q2 + pe2 + e2;
      o.w = a[3] + q3 + pe3 + e3;
      *reinterpret_cast<float4*>(out + (size_t)row * D_DIM + colq) = o;
    }
  }
}

extern "C" void kernel_launch(void* const* d_in, const int* in_sizes, int n_in,
                              void* d_out, int out_size, void* d_ws,
                              size_t ws_size, hipStream_t stream) {
  const float* x = (const float*)d_in[0];
  const float* W = (const float*)d_in[1];
  const float* b_emb = (const float*)d_in[2];
  const float* w_seg = (const float*)d_in[3];
  const float* b_seg = (const float*)d_in[4];
  float* out = (float*)d_out;

  unsigned short* wsW = (unsigned short*)d_ws;                      // 128 KB
  unsigned short* wsX = (unsigned short*)((char*)d_ws + WS_X_OFF);  // 4 MB

  bert_setup<<<1056, 256, 0, stream>>>(x, W, wsW, wsX);
  bert_main<<<4096, 256, 0, stream>>>(wsX, wsW, b_emb, w_seg, b_seg, out);
}